// Round 1
// baseline (362.591 us; speedup 1.0000x reference)
//
#include <hip/hip_runtime.h>
#include <stdint.h>

#define M_DIM 16384
#define N_DIM 4096
#define K_DIM 512

#define BM 128
#define BN 128
#define BK 64
#define LDS_STRIDE 72  // 64 bf16 + 8 pad (16 B) -> conflict-free ds_read_b128

typedef __bf16 bf16x8 __attribute__((ext_vector_type(8)));
typedef float f32x4 __attribute__((ext_vector_type(4)));

// pack two fp32 -> bf16x2 by truncation (1 v_perm_b32).
// sel 0x07060302: dest = [hi16(S1), hi16(S0)] with S1 = lo arg
__device__ __forceinline__ unsigned pack_bf16(float lo, float hi) {
    return __builtin_amdgcn_perm(__float_as_uint(hi), __float_as_uint(lo), 0x07060302u);
}

// one wave per row: sum of squares of 512 fp32
__global__ void row_norms_kernel(const float* __restrict__ src,
                                 float* __restrict__ dst, int nrows) {
    int wave = threadIdx.x >> 6;
    int lane = threadIdx.x & 63;
    int row = blockIdx.x * 4 + wave;
    if (row >= nrows) return;
    const float4* p = (const float4*)(src + (size_t)row * K_DIM);
    float4 a = p[lane];
    float4 b = p[lane + 64];
    float s = a.x*a.x + a.y*a.y + a.z*a.z + a.w*a.w
            + b.x*b.x + b.y*b.y + b.z*b.z + b.w*b.w;
    #pragma unroll
    for (int off = 32; off > 0; off >>= 1) s += __shfl_down(s, off, 64);
    if (lane == 0) dst[row] = s;
}

__global__ __launch_bounds__(256)
void rbf_mfma_kernel(const float* __restrict__ X, const float* __restrict__ C,
                     const float* __restrict__ xsq, const float* __restrict__ csq,
                     float* __restrict__ out) {
    __shared__ uint16_t As[BM * LDS_STRIDE];
    __shared__ uint16_t Bs[BN * LDS_STRIDE];

    const int tid  = threadIdx.x;
    const int lane = tid & 63;
    const int wave = tid >> 6;
    const int wm = (wave >> 1) * 64;   // wave's 64-row slab within the 128-tile
    const int wn = (wave & 1) * 64;    // wave's 64-col slab
    const int q   = lane >> 4;         // quad 0..3
    const int c16 = lane & 15;

    const int bn = (blockIdx.x & 31) * BN;  // 4096/128 = 32 col-blocks (fastest -> B reuse)
    const int bm = (blockIdx.x >> 5) * BM;  // 128 row-blocks

    // staging map: 8 threads per row, each thread 8 consecutive k (16 B bf16 out)
    const int srow  = tid >> 3;        // 0..31 (x4 passes -> 128 rows)
    const int skoff = (tid & 7) * 8;   // 0..56

    f32x4 acc[4][4] = {};

    const float* Abase = X + (size_t)(bm + srow) * K_DIM + skoff;
    const float* Bbase = C + (size_t)(bn + srow) * K_DIM + skoff;

    for (int k0 = 0; k0 < K_DIM; k0 += BK) {
        #pragma unroll
        for (int p = 0; p < 4; ++p) {
            const float4* ap = (const float4*)(Abase + (size_t)(32 * p) * K_DIM + k0);
            float4 f0 = ap[0], f1 = ap[1];
            uint4 ua;
            ua.x = pack_bf16(f0.x, f0.y);
            ua.y = pack_bf16(f0.z, f0.w);
            ua.z = pack_bf16(f1.x, f1.y);
            ua.w = pack_bf16(f1.z, f1.w);
            *(uint4*)&As[(srow + 32 * p) * LDS_STRIDE + skoff] = ua;

            const float4* bp = (const float4*)(Bbase + (size_t)(32 * p) * K_DIM + k0);
            float4 g0 = bp[0], g1 = bp[1];
            uint4 ub;
            ub.x = pack_bf16(g0.x, g0.y);
            ub.y = pack_bf16(g0.z, g0.w);
            ub.z = pack_bf16(g1.x, g1.y);
            ub.w = pack_bf16(g1.z, g1.w);
            *(uint4*)&Bs[(srow + 32 * p) * LDS_STRIDE + skoff] = ub;
        }
        __syncthreads();

        #pragma unroll
        for (int ks = 0; ks < 2; ++ks) {   // two 32-wide k-steps per BK=64
            bf16x8 af[4], bfr[4];
            #pragma unroll
            for (int i = 0; i < 4; ++i)
                af[i] = *(const bf16x8*)&As[(wm + 16 * i + c16) * LDS_STRIDE + ks * 32 + q * 8];
            #pragma unroll
            for (int j = 0; j < 4; ++j)
                bfr[j] = *(const bf16x8*)&Bs[(wn + 16 * j + c16) * LDS_STRIDE + ks * 32 + q * 8];
            #pragma unroll
            for (int i = 0; i < 4; ++i)
                #pragma unroll
                for (int j = 0; j < 4; ++j)
                    acc[i][j] = __builtin_amdgcn_mfma_f32_16x16x32_bf16(
                        af[i], bfr[j], acc[i][j], 0, 0, 0);
        }
        __syncthreads();
    }

    // epilogue: dist = xsq - 2*cross + csq ; out = exp(-dist)
    float cs[4];
    #pragma unroll
    for (int j = 0; j < 4; ++j) cs[j] = csq[bn + wn + 16 * j + c16];

    #pragma unroll
    for (int i = 0; i < 4; ++i) {
        #pragma unroll
        for (int r = 0; r < 4; ++r) {
            int m = bm + wm + 16 * i + q * 4 + r;   // C/D: row=(lane>>4)*4+reg, col=lane&15
            float xs = xsq[m];
            float* orow = out + (size_t)m * N_DIM + bn + wn;
            #pragma unroll
            for (int j = 0; j < 4; ++j) {
                float dist = xs - 2.0f * acc[i][j][r] + cs[j];
                orow[16 * j + c16] = __expf(-dist);
            }
        }
    }
}

extern "C" void kernel_launch(void* const* d_in, const int* in_sizes, int n_in,
                              void* d_out, int out_size, void* d_ws, size_t ws_size,
                              hipStream_t stream) {
    const float* X = (const float*)d_in[0];
    const float* C = (const float*)d_in[1];
    float* out = (float*)d_out;
    float* xsq = (float*)d_ws;          // 16384 floats
    float* csq = xsq + M_DIM;           // 4096 floats (80 KB total << ws)

    row_norms_kernel<<<M_DIM / 4, 256, 0, stream>>>(X, xsq, M_DIM);
    row_norms_kernel<<<N_DIM / 4, 256, 0, stream>>>(C, csq, N_DIM);
    rbf_mfma_kernel<<<(M_DIM / BM) * (N_DIM / BN), 256, 0, stream>>>(X, C, xsq, csq, out);
}

// Round 2
// 343.664 us; speedup vs baseline: 1.0551x; 1.0551x over previous
//
#include <hip/hip_runtime.h>
#include <stdint.h>

#define M_DIM 16384
#define N_DIM 4096
#define K_DIM 512
#define KB2 1024            // bf16 row bytes (512 * 2)

#define BM 128
#define BN 256
#define BK 64

typedef __bf16 bf16x8 __attribute__((ext_vector_type(8)));
typedef float f32x16 __attribute__((ext_vector_type(16)));

typedef __attribute__((address_space(3))) uint32_t lds_u32_t;
typedef const __attribute__((address_space(1))) uint32_t glob_u32_t;

__device__ __forceinline__ void gload16(const void* g, void* l) {
    __builtin_amdgcn_global_load_lds((glob_u32_t*)g, (lds_u32_t*)l, 16, 0, 0);
}

// pack two fp32 -> bf16x2 by truncation (1 v_perm_b32)
__device__ __forceinline__ unsigned pack_bf16(float lo, float hi) {
    return __builtin_amdgcn_perm(__float_as_uint(hi), __float_as_uint(lo), 0x07060302u);
}

// one wave per row: fp32 row -> bf16 row (16 B/lane) + sum of squares
__global__ __launch_bounds__(256)
void convert_norm_kernel(const float* __restrict__ src, uint16_t* __restrict__ dst,
                         float* __restrict__ norms, int nrows) {
    const int wave = threadIdx.x >> 6;
    const int lane = threadIdx.x & 63;
    const int row = blockIdx.x * 4 + wave;
    if (row >= nrows) return;
    const float4* p = (const float4*)(src + (size_t)row * K_DIM) + lane * 2;
    float4 a = p[0], b = p[1];
    uint4 u;
    u.x = pack_bf16(a.x, a.y);
    u.y = pack_bf16(a.z, a.w);
    u.z = pack_bf16(b.x, b.y);
    u.w = pack_bf16(b.z, b.w);
    *(uint4*)(dst + (size_t)row * K_DIM + lane * 8) = u;
    float s = a.x*a.x + a.y*a.y + a.z*a.z + a.w*a.w
            + b.x*b.x + b.y*b.y + b.z*b.z + b.w*b.w;
    #pragma unroll
    for (int off = 32; off > 0; off >>= 1) s += __shfl_down(s, off, 64);
    if (lane == 0) norms[row] = s;
}

// Block 128x256, 4 waves 2x2, wave tile 64x128 (2x4 of 32x32x16 MFMA).
// LDS: unpadded rows of 64 bf16 (128 B), chunk-XOR-swizzled so ds_read_b128
// fragment reads are bank-conflict-free without padding.
__global__ __launch_bounds__(256, 2)
void rbf_mfma_kernel(const uint16_t* __restrict__ Abf, const uint16_t* __restrict__ Bbf,
                     const float* __restrict__ xsq, const float* __restrict__ csq,
                     float* __restrict__ out) {
    __shared__ uint16_t As[BM * BK];   // 16 KB
    __shared__ uint16_t Bs[BN * BK];   // 32 KB

    const int tid  = threadIdx.x;
    const int lane = tid & 63;
    const int wave = tid >> 6;
    const int l31  = lane & 31;
    const int half = lane >> 5;
    const int l7   = lane & 7;

    const int bn = (blockIdx.x & 15) * BN;   // 16 col-blocks (inner -> A-tile reuse in L2)
    const int bm = (blockIdx.x >> 4) * BM;

    const int wm = (wave >> 1) * 64;    // wave row slab (64 rows)
    const int wn = (wave & 1) * 128;    // wave col slab (128 cols)

    // ---- staging map: thread -> (row srow, swizzled 16B chunk schunk) ----
    const int srow   = tid >> 3;                 // 0..31 per round
    const int schunk = (tid & 7) ^ (srow & 7);   // XOR swizzle
    const size_t soff = (size_t)srow * KB2 + (size_t)schunk * 16;

    const uint8_t* pA = (const uint8_t*)Abf + (size_t)bm * KB2 + soff;
    const uint8_t* pB = (const uint8_t*)Bbf + (size_t)bn * KB2 + soff;
    uint8_t* AsB = (uint8_t*)As;
    uint8_t* BsB = (uint8_t*)Bs;

    // ---- fragment-read bases (k-iter invariant) ----
    // element offset of 8-bf16 fragment: row * BK + slot*8, slot = (ks*2+half) ^ l7
    const uint16_t* Arow = As + (wm + l31) * BK;
    const uint16_t* Brow = Bs + (wn + l31) * BK;
    int slot[4];
    #pragma unroll
    for (int ks = 0; ks < 4; ++ks) slot[ks] = (((ks * 2 + half) ^ l7) * 8);

    f32x16 acc[2][4] = {};   // 128 VGPRs

    for (int kk = 0; kk < K_DIM / BK; ++kk) {
        // stage A (4 rounds) + B (8 rounds); each round: 256 lanes x 16 B
        #pragma unroll
        for (int t = 0; t < 4; ++t)
            gload16(pA + (size_t)t * 32 * KB2, AsB + t * 4096 + wave * 1024);
        #pragma unroll
        for (int t = 0; t < 8; ++t)
            gload16(pB + (size_t)t * 32 * KB2, BsB + t * 4096 + wave * 1024);
        pA += BK * 2;   // advance 64 bf16 = 128 B
        pB += BK * 2;
        __syncthreads();

        #pragma unroll
        for (int ks = 0; ks < 4; ++ks) {
            bf16x8 af[2], bfr[4];
            #pragma unroll
            for (int i = 0; i < 2; ++i)
                af[i] = *(const bf16x8*)(Arow + i * 32 * BK + slot[ks]);
            #pragma unroll
            for (int j = 0; j < 4; ++j)
                bfr[j] = *(const bf16x8*)(Brow + j * 32 * BK + slot[ks]);
            #pragma unroll
            for (int i = 0; i < 2; ++i)
                #pragma unroll
                for (int j = 0; j < 4; ++j)
                    acc[i][j] = __builtin_amdgcn_mfma_f32_32x32x16_bf16(
                        af[i], bfr[j], acc[i][j], 0, 0, 0);
        }
        __syncthreads();
    }

    // ---- epilogue: out = exp(-(xsq - 2*cross + csq)) ----
    // C/D 32x32 layout: col = lane&31, row = (reg&3) + 8*(reg>>2) + 4*(lane>>5)
    float cs[4];
    #pragma unroll
    for (int j = 0; j < 4; ++j) cs[j] = csq[bn + wn + 32 * j + l31];

    #pragma unroll
    for (int i = 0; i < 2; ++i) {
        #pragma unroll
        for (int r = 0; r < 16; ++r) {
            const int gm = bm + wm + 32 * i + 4 * half + (r & 3) + 8 * (r >> 2);
            const float xs = xsq[gm];
            float* orow = out + (size_t)gm * N_DIM + bn + wn;
            #pragma unroll
            for (int j = 0; j < 4; ++j) {
                float d = xs - 2.0f * acc[i][j][r] + cs[j];
                orow[32 * j + l31] = __expf(-d);
            }
        }
    }
}

extern "C" void kernel_launch(void* const* d_in, const int* in_sizes, int n_in,
                              void* d_out, int out_size, void* d_ws, size_t ws_size,
                              hipStream_t stream) {
    const float* X = (const float*)d_in[0];
    const float* C = (const float*)d_in[1];
    float* out = (float*)d_out;

    uint16_t* Xbf = (uint16_t*)d_ws;                          // 16 MB
    uint16_t* Cbf = Xbf + (size_t)M_DIM * K_DIM;              // 4 MB
    float* xsq = (float*)(Cbf + (size_t)N_DIM * K_DIM);       // 64 KB
    float* csq = xsq + M_DIM;                                 // 16 KB

    convert_norm_kernel<<<M_DIM / 4, 256, 0, stream>>>(X, Xbf, xsq, M_DIM);
    convert_norm_kernel<<<N_DIM / 4, 256, 0, stream>>>(C, Cbf, csq, N_DIM);
    rbf_mfma_kernel<<<(M_DIM / BM) * (N_DIM / BN), 256, 0, stream>>>(Xbf, Cbf, xsq, csq, out);
}

// Round 3
// 308.946 us; speedup vs baseline: 1.1736x; 1.1124x over previous
//
#include <hip/hip_runtime.h>
#include <stdint.h>

#define M_DIM 16384
#define N_DIM 4096
#define K_DIM 512

#define BM 128
#define BN 256
#define BK 128

typedef int v8i __attribute__((ext_vector_type(8)));
typedef float f32x16 __attribute__((ext_vector_type(16)));

typedef __attribute__((address_space(3))) uint32_t lds_u32_t;
typedef const __attribute__((address_space(1))) uint32_t glob_u32_t;

__device__ __forceinline__ void gload16(const void* g, void* l) {
    __builtin_amdgcn_global_load_lds((glob_u32_t*)g, (lds_u32_t*)l, 16, 0, 0);
}

// one wave per row: fp32 row -> fp8 e4m3 row (8 B/lane) + fp32 sum of squares.
// Handles X rows [0, M) and C rows [M, M+N) in one launch.
__global__ __launch_bounds__(256)
void convert_norm_kernel(const float* __restrict__ X, const float* __restrict__ C,
                         uint8_t* __restrict__ Xf8, uint8_t* __restrict__ Cf8,
                         float* __restrict__ xsq, float* __restrict__ csq) {
    const int wave = threadIdx.x >> 6;
    const int lane = threadIdx.x & 63;
    const int row = blockIdx.x * 4 + wave;
    const float* src;
    uint8_t* dst;
    float* nrm;
    int r;
    if (row < M_DIM) { src = X; dst = Xf8; nrm = xsq; r = row; }
    else             { src = C; dst = Cf8; nrm = csq; r = row - M_DIM; }

    const float4* p = (const float4*)(src + (size_t)r * K_DIM) + lane * 2;
    float4 a = p[0], b = p[1];
    uint32_t lo = 0, hi = 0;
    lo = __builtin_amdgcn_cvt_pk_fp8_f32(a.x, a.y, lo, false);
    lo = __builtin_amdgcn_cvt_pk_fp8_f32(a.z, a.w, lo, true);
    hi = __builtin_amdgcn_cvt_pk_fp8_f32(b.x, b.y, hi, false);
    hi = __builtin_amdgcn_cvt_pk_fp8_f32(b.z, b.w, hi, true);
    *(uint2*)(dst + (size_t)r * K_DIM + lane * 8) = make_uint2(lo, hi);

    float s = a.x*a.x + a.y*a.y + a.z*a.z + a.w*a.w
            + b.x*b.x + b.y*b.y + b.z*b.z + b.w*b.w;
    #pragma unroll
    for (int off = 32; off > 0; off >>= 1) s += __shfl_down(s, off, 64);
    if (lane == 0) nrm[r] = s;
}

// Block 128x256, 4 waves 2x2, wave tile 64x128 = 2x4 of mfma_scale 32x32x64 fp8.
// LDS layout (per 32-row panel of 256 16B-chunks): chunk(r, kc) at r*8 + ((kc+r)&7)
// -> conflict-free ds_read_b128 AND realizable by global_load_lds (per-lane global
//    address freedom; LDS side is lane-contiguous as required).
// k-slot mapping is any fixed bijection applied identically to A and B fragments:
// dot over k is permutation-invariant, so exact HW k-wiring doesn't matter.
__global__ __launch_bounds__(256, 2)
void rbf_mfma_kernel(const uint8_t* __restrict__ A8, const uint8_t* __restrict__ B8,
                     const float* __restrict__ xsq, const float* __restrict__ csq,
                     float* __restrict__ out) {
    __shared__ uint8_t As[BM * BK];   // 16 KB  (4 panels x 4 KB)
    __shared__ uint8_t Bs[BN * BK];   // 32 KB  (8 panels x 4 KB)

    const int tid  = threadIdx.x;
    const int lane = tid & 63;
    const int wave = tid >> 6;
    const int h    = lane >> 5;
    const int r31  = lane & 31;

    const int bn = (blockIdx.x & 15) * BN;   // inner -> A-tile L2 reuse
    const int bm = (blockIdx.x >> 4) * BM;

    const int wm = (wave >> 1) * 64;
    const int wn = (wave & 1) * 128;

    // staging map: thread t covers panel-local chunk t each round
    const int sr  = tid >> 3;                     // row within panel 0..31
    const int skc = ((tid & 7) - sr) & 7;         // inverted swizzle -> global k-chunk
    const uint8_t* pA = A8 + (size_t)(bm + sr) * K_DIM + skc * 16;
    const uint8_t* pB = B8 + (size_t)(bn + sr) * K_DIM + skc * 16;
    uint8_t* AsW = As + wave * 1024;
    uint8_t* BsW = Bs + wave * 1024;

    f32x16 acc[2][4] = {};   // 128 VGPRs

    for (int k0 = 0; k0 < K_DIM; k0 += BK) {
        #pragma unroll
        for (int R = 0; R < 4; ++R)
            gload16(pA + k0 + (size_t)R * 32 * K_DIM, AsW + R * 4096);
        #pragma unroll
        for (int R = 0; R < 8; ++R)
            gload16(pB + k0 + (size_t)R * 32 * K_DIM, BsW + R * 4096);
        __syncthreads();

        #pragma unroll
        for (int ks = 0; ks < 2; ++ks) {
            v8i av[2], bv[4];
            #pragma unroll
            for (int i = 0; i < 2; ++i) {
                const int panel = (wm >> 5) + i;
                uint4 lo = *(const uint4*)(As + (panel * 256 + r31 * 8 + ((ks * 4 + 2 * h + 0 + r31) & 7)) * 16);
                uint4 hi = *(const uint4*)(As + (panel * 256 + r31 * 8 + ((ks * 4 + 2 * h + 1 + r31) & 7)) * 16);
                av[i] = (v8i){(int)lo.x, (int)lo.y, (int)lo.z, (int)lo.w,
                              (int)hi.x, (int)hi.y, (int)hi.z, (int)hi.w};
            }
            #pragma unroll
            for (int j = 0; j < 4; ++j) {
                const int panel = (wn >> 5) + j;
                uint4 lo = *(const uint4*)(Bs + (panel * 256 + r31 * 8 + ((ks * 4 + 2 * h + 0 + r31) & 7)) * 16);
                uint4 hi = *(const uint4*)(Bs + (panel * 256 + r31 * 8 + ((ks * 4 + 2 * h + 1 + r31) & 7)) * 16);
                bv[j] = (v8i){(int)lo.x, (int)lo.y, (int)lo.z, (int)lo.w,
                              (int)hi.x, (int)hi.y, (int)hi.z, (int)hi.w};
            }
            #pragma unroll
            for (int i = 0; i < 2; ++i)
                #pragma unroll
                for (int j = 0; j < 4; ++j)
                    acc[i][j] = __builtin_amdgcn_mfma_scale_f32_32x32x64_f8f6f4(
                        av[i], bv[j], acc[i][j],
                        0 /*cbsz: fp8 e4m3*/, 0 /*blgp: fp8 e4m3*/,
                        0, 0x7F7F7F7Fu /*scale_a = 2^0*/,
                        0, 0x7F7F7F7Fu /*scale_b = 2^0*/);
        }
        __syncthreads();
    }

    // epilogue: out = exp(-(xsq - 2*cross + csq))
    // C/D 32x32: col = lane&31, row = (reg&3) + 8*(reg>>2) + 4*(lane>>5)
    float cs[4];
    #pragma unroll
    for (int j = 0; j < 4; ++j) cs[j] = csq[bn + wn + 32 * j + r31];

    #pragma unroll
    for (int i = 0; i < 2; ++i) {
        #pragma unroll
        for (int r = 0; r < 16; ++r) {
            const int gm = bm + wm + 32 * i + 4 * h + (r & 3) + 8 * (r >> 2);
            const float xs = xsq[gm];
            float* orow = out + (size_t)gm * N_DIM + bn + wn;
            #pragma unroll
            for (int j = 0; j < 4; ++j) {
                float d = xs - 2.0f * acc[i][j][r] + cs[j];
                orow[32 * j + r31] = __expf(-d);
            }
        }
    }
}

extern "C" void kernel_launch(void* const* d_in, const int* in_sizes, int n_in,
                              void* d_out, int out_size, void* d_ws, size_t ws_size,
                              hipStream_t stream) {
    const float* X = (const float*)d_in[0];
    const float* C = (const float*)d_in[1];
    float* out = (float*)d_out;

    uint8_t* Xf8 = (uint8_t*)d_ws;                            // 8 MB
    uint8_t* Cf8 = Xf8 + (size_t)M_DIM * K_DIM;               // 2 MB
    float* xsq = (float*)(Cf8 + (size_t)N_DIM * K_DIM);       // 64 KB
    float* csq = xsq + M_DIM;                                 // 16 KB

    convert_norm_kernel<<<(M_DIM + N_DIM) / 4, 256, 0, stream>>>(X, C, Xf8, Cf8, xsq, csq);
    rbf_mfma_kernel<<<(M_DIM / BM) * (N_DIM / BN), 256, 0, stream>>>(Xf8, Cf8, xsq, csq, out);
}